// Round 1
// 742.094 us; speedup vs baseline: 1.0065x; 1.0065x over previous
//
#include <hip/hip_runtime.h>
#include <hip/hip_bf16.h>
#include <math.h>
#include <stdint.h>

#define B_   2
#define T_   1024
#define HID_ 2048
#define H_   16
#define DK_  128
#define DV_  128
#define TS_  16     // timesteps staged per LDS tile in recurrence

typedef __bf16 bf16;
typedef __attribute__((ext_vector_type(8))) __bf16 bf16x8;
typedef __attribute__((ext_vector_type(4))) float f32x4;

typedef __attribute__((address_space(3))) uint32_t* lds_ptr_t;
typedef const __attribute__((address_space(1))) uint32_t* glb_ptr_t;

__device__ __forceinline__ float sigmoidf_(float x) {
    return 1.0f / (1.0f + __expf(-x));
}

// async global->LDS, 16B per lane. LDS base wave-uniform (HW: lane i ->
// base + 16*i); global address is per-lane.
__device__ __forceinline__ void ldg_to_lds16(const void* g, void* lds) {
    __builtin_amdgcn_global_load_lds((glb_ptr_t)(uintptr_t)g,
                                     (lds_ptr_t)(uintptr_t)lds, 16, 0, 0);
}

// DPP rotate-add: VALU-latency cross-lane. CTRL = 0x120 + n (row_ror:n).
template <int CTRL>
__device__ __forceinline__ float dpp_ror_add(float x) {
    int yi = __builtin_amdgcn_update_dpp(
        0, __builtin_bit_cast(int, x), CTRL, 0xF, 0xF, true);
    return x + __builtin_bit_cast(float, yi);
}
// all-reduce (sum) across the 16 lanes of a DPP row
__device__ __forceinline__ float row16_allreduce(float x) {
    x = dpp_ror_add<0x128>(x);   // ror 8
    x = dpp_ror_add<0x124>(x);   // ror 4
    x = dpp_ror_add<0x122>(x);   // ror 2
    x = dpp_ror_add<0x121>(x);   // ror 1
    return x;
}

// ---------------------------------------------------------------------------
// fp32 -> bf16 elementwise cast, 8 elems/thread
// ---------------------------------------------------------------------------
__global__ __launch_bounds__(256) void cast_bf16_kernel(
    const float* __restrict__ in, bf16* __restrict__ out)
{
    int i = blockIdx.x * 256 + threadIdx.x;
    float4 a = ((const float4*)in)[2 * i];
    float4 b = ((const float4*)in)[2 * i + 1];
    bf16x8 o;
    o[0] = (bf16)a.x; o[1] = (bf16)a.y; o[2] = (bf16)a.z; o[3] = (bf16)a.w;
    o[4] = (bf16)b.x; o[5] = (bf16)b.y; o[6] = (bf16)b.z; o[7] = (bf16)b.w;
    ((bf16x8*)out)[i] = o;
}

// ---------------------------------------------------------------------------
// W [K,N] fp32  ->  Wt [N,K] bf16 (transpose-cast). 32x32 tiles.
// ---------------------------------------------------------------------------
__global__ __launch_bounds__(256) void tcast_kernel(
    const float* __restrict__ W, bf16* __restrict__ Wt, int K, int N)
{
    __shared__ float tile[32][33];
    const int k0 = blockIdx.y * 32, n0 = blockIdx.x * 32;
    const int r = threadIdx.x >> 5, c = threadIdx.x & 31;
    #pragma unroll
    for (int i = 0; i < 4; ++i)
        tile[r + 8 * i][c] = W[(size_t)(k0 + r + 8 * i) * N + n0 + c];
    __syncthreads();
    #pragma unroll
    for (int i = 0; i < 4; ++i)
        Wt[(size_t)(n0 + r + 8 * i) * K + k0 + c] = (bf16)tile[c][r + 8 * i];
}

// ---------------------------------------------------------------------------
// Transpose-cast with row/col offset + sign into Wt with row-stride 256.
// W [128, N] fp32 -> Wt[(noff+n)*256 + koff + k] = sign * W[k][n].
// Used to build [Wgb2; +/-Wgd2] concatenated K=256 weights.
// ---------------------------------------------------------------------------
__global__ __launch_bounds__(256) void tcast_off_kernel(
    const float* __restrict__ W, bf16* __restrict__ Wt,
    int N, int noff, int koff, float sign)
{
    __shared__ float tile[32][33];
    const int k0 = blockIdx.y * 32, n0 = blockIdx.x * 32;
    const int r = threadIdx.x >> 5, c = threadIdx.x & 31;
    #pragma unroll
    for (int i = 0; i < 4; ++i)
        tile[r + 8 * i][c] = W[(size_t)(k0 + r + 8 * i) * N + n0 + c];
    __syncthreads();
    #pragma unroll
    for (int i = 0; i < 4; ++i)
        Wt[(size_t)(noff + n0 + r + 8 * i) * 256 + koff + k0 + c] =
            (bf16)(sign * tile[c][r + 8 * i]);
}

// ---------------------------------------------------------------------------
// bf16 MFMA GEMM: C[M,N] = A[M,K] @ Bt[N,K]^T (+bias). 128x128 tile, BK=32.
// lda/ldc = element row strides of A/C; Bt row stride = Kfull.
// ---------------------------------------------------------------------------
__global__ __launch_bounds__(256) void mfma_gemm_kernel(
    const bf16* __restrict__ A, const bf16* __restrict__ Bt,
    const float* __restrict__ bias, void* __restrict__ Cout,
    int M, int N, int Kfull, int lda, int ldc, int bf16out)
{
    __shared__ bf16 As[128 * 32];
    __shared__ bf16 Bs[128 * 32];

    const int tid  = threadIdx.x;
    const int w    = tid >> 6;
    const int lane = tid & 63;
    const int n0   = blockIdx.x * 128;
    const int m0   = blockIdx.y * 128;
    const int wm   = (w >> 1) * 64;
    const int wn   = (w & 1) * 64;

    const int lr = lane >> 2;
    const int lc = (lane & 3) * 8;

    f32x4 acc[4][4];
    #pragma unroll
    for (int i = 0; i < 4; ++i)
        #pragma unroll
        for (int j = 0; j < 4; ++j) acc[i][j] = (f32x4)0.0f;

    const bf16* ApL = As + (wm + (lane & 15)) * 32 + (lane >> 4) * 8;
    const bf16* BpL = Bs + (wn + (lane & 15)) * 32 + (lane >> 4) * 8;

    for (int k0 = 0; k0 < Kfull; k0 += 32) {
        #pragma unroll
        for (int i = 0; i < 2; ++i) {
            const int rr = (w * 2 + i) * 16 + lr;
            ldg_to_lds16(A  + (size_t)(m0 + rr) * lda   + k0 + lc, As + (w * 2 + i) * 512);
            ldg_to_lds16(Bt + (size_t)(n0 + rr) * Kfull + k0 + lc, Bs + (w * 2 + i) * 512);
        }
        __syncthreads();

        bf16x8 af[4], bfr[4];
        #pragma unroll
        for (int i = 0; i < 4; ++i) af[i]  = *(const bf16x8*)(ApL + i * 16 * 32);
        #pragma unroll
        for (int j = 0; j < 4; ++j) bfr[j] = *(const bf16x8*)(BpL + j * 16 * 32);
        #pragma unroll
        for (int i = 0; i < 4; ++i)
            #pragma unroll
            for (int j = 0; j < 4; ++j)
                acc[i][j] = __builtin_amdgcn_mfma_f32_16x16x32_bf16(
                    af[i], bfr[j], acc[i][j], 0, 0, 0);
        __syncthreads();
    }

    #pragma unroll
    for (int i = 0; i < 4; ++i) {
        const int row = m0 + wm + i * 16 + (lane >> 4) * 4;
        #pragma unroll
        for (int j = 0; j < 4; ++j) {
            const int col = n0 + wn + j * 16 + (lane & 15);
            const float bv = bias ? bias[col] : 0.0f;
            #pragma unroll
            for (int r = 0; r < 4; ++r) {
                float v = acc[i][j][r] + bv;
                if (bf16out) ((bf16*)Cout)[(size_t)(row + r) * ldc + col] = (bf16)v;
                else ((float*)Cout)[(size_t)(row + r) * ldc + col] = v;
            }
        }
    }
}

// ---------------------------------------------------------------------------
// Cast mid slice of mega-GEMM output (cols 6144..6527 of [M,6528]) -> bf16
// midb [M,384]. 4 cols/thread.
// ---------------------------------------------------------------------------
__global__ __launch_bounds__(256) void midcast_kernel(
    const float* __restrict__ src, bf16* __restrict__ midb)
{
    int i = blockIdx.x * 256 + threadIdx.x;   // over 2048*96
    int m = i / 96, c4 = i - m * 96;
    float4 v = *(const float4*)(src + (size_t)m * 6528 + 6144 + c4 * 4);
    bf16 o[4] = {(bf16)v.x, (bf16)v.y, (bf16)v.z, (bf16)v.w};
    *(uint64_t*)(midb + (size_t)m * 384 + c4 * 4) = *(uint64_t*)o;
}

// ---------------------------------------------------------------------------
// Fused skinny GEMMs: bb/bd/lam = x @ {Wbb,Wbd,Wlam}  (N=16 each, K=2048).
// ---------------------------------------------------------------------------
__global__ __launch_bounds__(256) void skinny3_kernel(
    const float* __restrict__ x, const float* __restrict__ Wbb,
    const float* __restrict__ Wbd, const float* __restrict__ Wlam,
    float* __restrict__ bb, float* __restrict__ bd, float* __restrict__ lam)
{
    __shared__ float xs[16][128];
    __shared__ float wsh[128][48];
    const int m0  = blockIdx.x * 16;
    const int tid = threadIdx.x;
    const int r = tid >> 4, cg = tid & 15;
    float acc0 = 0.f, acc1 = 0.f, acc2 = 0.f;

    for (int k0 = 0; k0 < HID_; k0 += 128) {
        __syncthreads();
        #pragma unroll
        for (int i = 0; i < 2; ++i) {
            int f = tid + 256 * i;
            int rr = f >> 5, cc = (f & 31) * 4;
            *(float4*)&xs[rr][cc] = *(const float4*)(x + (size_t)(m0 + rr) * HID_ + k0 + cc);
        }
        #pragma unroll
        for (int i = 0; i < 2; ++i) {
            int f = tid + 256 * i;
            int kk = f >> 2, cc = (f & 3) * 4;
            *(float4*)&wsh[kk][cc]      = *(const float4*)(Wbb  + (size_t)(k0 + kk) * 16 + cc);
            *(float4*)&wsh[kk][16 + cc] = *(const float4*)(Wbd  + (size_t)(k0 + kk) * 16 + cc);
            *(float4*)&wsh[kk][32 + cc] = *(const float4*)(Wlam + (size_t)(k0 + kk) * 16 + cc);
        }
        __syncthreads();
        #pragma unroll 8
        for (int kk = 0; kk < 128; ++kk) {
            float xv = xs[r][kk];
            acc0 += xv * wsh[kk][cg];
            acc1 += xv * wsh[kk][16 + cg];
            acc2 += xv * wsh[kk][32 + cg];
        }
    }
    size_t o = (size_t)(m0 + r) * 16 + cg;
    bb[o] = acc0; bd[o] = acc1; lam[o] = acc2;
}

// ---------------------------------------------------------------------------
// Causal depthwise conv1d (K=4) + SiLU, + optional per-head l2norm.
// Reads strided slice of mega-GEMM pre-activations. fp32 out.
// mode: 0 = silu only (v); 1 = + l2norm (k); 2 = + l2norm * DK^-0.5 (q)
// ---------------------------------------------------------------------------
__global__ __launch_bounds__(256) void conv_silu_kernel(
    const float* __restrict__ xin, int ldx, int coloff,
    const float* __restrict__ w, float* __restrict__ yout, int mode)
{
    const int bt  = blockIdx.x;
    const int t   = bt & (T_ - 1);
    const int tid = threadIdx.x;
    const float* xr = xin + (size_t)bt * ldx + coloff;

    float val[8];
    #pragma unroll
    for (int jj = 0; jj < 8; ++jj) {
        int c = tid + 256 * jj;
        float4 wc = *(const float4*)(w + (size_t)c * 4);
        const float* xc = xr + c;
        float acc = wc.w * xc[0];
        if (t >= 1) acc += wc.z * xc[-ldx];
        if (t >= 2) acc += wc.y * xc[-2 * ldx];
        if (t >= 3) acc += wc.x * xc[-3 * ldx];
        val[jj] = acc * sigmoidf_(acc);
    }

    if (mode > 0) {
        __shared__ float red[4][8];
        const int wv = tid >> 6;
        #pragma unroll
        for (int jj = 0; jj < 8; ++jj) {
            float v2 = val[jj] * val[jj];
            #pragma unroll
            for (int m = 1; m < 64; m <<= 1) v2 += __shfl_xor(v2, m);
            if ((tid & 63) == 0) red[wv][jj] = v2;
        }
        __syncthreads();
        const int wb = (tid >> 7) * 2;
        #pragma unroll
        for (int jj = 0; jj < 8; ++jj) {
            float ss = red[wb][jj] + red[wb + 1][jj];
            float sc = rsqrtf(ss + 1e-6f);
            if (mode == 2) sc *= 0.08838834764831845f;     // DK^-0.5
            val[jj] *= sc;
        }
    }

    const size_t row = (size_t)bt * HID_;
    #pragma unroll
    for (int jj = 0; jj < 8; ++jj)
        yout[row + tid + 256 * jj] = val[jj];
}

// ---------------------------------------------------------------------------
// Decay gates, in place on gfgs [M,4096] (cols 0..2047 = gf, 2048.. = gs):
// x <- exp(-exp(A_log[h]) * softplus(x + dtb))
// ---------------------------------------------------------------------------
__global__ __launch_bounds__(256) void decay_gate_kernel(
    float* gfgs, const float* __restrict__ A_log,
    const float* __restrict__ dt_bias)
{
    size_t i = (size_t)blockIdx.x * 256 + threadIdx.x;   // over M*2048
    int c = (int)(i & (HID_ - 1));
    size_t m = i >> 11;
    int h = c >> 7;
    float* pf = gfgs + m * 4096 + c;
    float* ps = pf + 2048;
    float na = -__expf(A_log[h]);
    float db = dt_bias[c];
    float xf = *pf + db;
    float xs = *ps + db;
    float spf = (xf > 20.0f) ? xf : log1pf(__expf(xf));
    float sps = (xs > 20.0f) ? xs : log1pf(__expf(xs));
    *pf = __expf(na * spf);
    *ps = __expf(na * sps);
}

// ---------------------------------------------------------------------------
// Dual-state gated delta-rule recurrence, v5: latency-hiding rewrite.
//  - double-buffered LDS tiles: tile t+1's global_load_lds issued right
//    after the barrier, flying under tile t's 16-step compute (never
//    exposed at the barrier drain).
//  - 2-deep register software pipeline over the 16 steps: step tt+1's six
//    ds_read_b128 issue before step tt's dependent chain (named A/B
//    register sets -> no scratch).
//  - OT buffer + second barrier removed: kseg==0 lanes store o directly
//    to global (16 contiguous floats/step). ONE __syncthreads per tile.
//  - V staged via global_load_lds; beta loads issue-early / use-late.
// Grid: 512 blocks: bx = sv*32 + bh;  bh = b*16+h, sv = s*8+vc.
// Block: 256 threads = 4 waves; wave = 4 cols x 16 ksegs (8 k-chan each).
// LDS slot layout per row (128 floats): slot l<16 holds channels 8l..8l+3,
// slot l>=16 holds 8(l-16)+4..8(l-16)+7  -> each b128 read is 2-way/bank.
// ---------------------------------------------------------------------------
struct StepRegs {
    float4 e0, e1, k0, k1, q0, q1;
    float v, bt;
};

__global__ __launch_bounds__(256) void fkda_kernel(
    const float* __restrict__ qp, const float* __restrict__ kp,
    const float* __restrict__ vp, const float* __restrict__ egf,
    const float* __restrict__ egs, int ldeg,
    const float* __restrict__ bbp, const float* __restrict__ bdp,
    float* __restrict__ ofp, float* __restrict__ osp)
{
    const int bx = blockIdx.x;
    const int bh = bx & 31;
    const int sv = bx >> 5;
    const int b  = bh >> 4;
    const int h  = bh & 15;
    const int s  = sv >> 3;
    const int vc = sv & 7;

    const float* eg = s ? egs : egf;
    float*       op = s ? osp : ofp;
    const float  bsign = s ? -1.0f : 1.0f;

    const int tid  = threadIdx.x;
    const int lane = tid & 63;
    const int w    = tid >> 6;
    const int kseg = lane & 15;
    const int colb = w * 4 + (lane >> 4);

    const size_t base  = (size_t)b * T_ * HID_ + (size_t)h * DK_;
    const size_t baseg = (size_t)b * T_ * ldeg + (size_t)h * DK_;
    const size_t ocol  = base + (size_t)vc * 16 + colb;

    __shared__ float EG[2][TS_ * 128];     // 8 KB each buf
    __shared__ float KK[2][TS_ * 128];
    __shared__ float QQ[2][TS_ * 128];
    __shared__ float VV[2][TS_ * 16];
    __shared__ float BT[2][TS_];

    float S[8];
    #pragma unroll
    for (int j = 0; j < 8; ++j) S[j] = 0.0f;

    // staging lane map: flat word W = n*256 + 4*lane must hold row tt's
    // swizzled slot; lane fetches the matching global channel.
    const int l5  = lane & 31;
    const int ttl = lane >> 5;
    const int cg  = (l5 < 16) ? (l5 * 8) : ((l5 - 16) * 8 + 4);
    const int sl  = kseg * 4;    // read slot word base

    // issue all async global->LDS staging for the tile starting at t0
    auto stage_glds = [&](int bi, int t0) {
        #pragma unroll
        for (int i = 0; i < 2; ++i) {
            int n  = w * 2 + i;
            int tt = n * 2 + ttl;
            size_t rq = base  + (size_t)(t0 + tt) * HID_ + cg;
            size_t rg = baseg + (size_t)(t0 + tt) * ldeg + cg;
            ldg_to_lds16(eg + rg, &EG[bi][n * 256]);
            ldg_to_lds16(kp + rq, &KK[bi][n * 256]);
            ldg_to_lds16(qp + rq, &QQ[bi][n * 256]);
        }
        if (tid < 64) {       // V: 16t x 16cols fp32, lane l -> tt=l>>2
            int tt2 = tid >> 2, vo = (tid & 3) * 4;
            size_t g = base + (size_t)(t0 + tt2) * HID_ + vc * 16 + vo;
            ldg_to_lds16(vp + g, &VV[bi][0]);
        }
    };

    // ---- prologue: stage tile 0 (incl. beta) ----
    float bbv = 0.0f, bdv = 0.0f;
    if (tid < TS_) {
        size_t gi = ((size_t)b * T_ + tid) * H_ + h;
        bbv = bbp[gi]; bdv = bdp[gi];
    }
    stage_glds(0, 0);
    if (tid < TS_) BT[0][tid] = sigmoidf_(bbv + bsign * bdv);

    for (int t0 = 0; t0 < T_; t0 += TS_) {
        const int cur = (t0 >> 4) & 1;
        const int nxt = cur ^ 1;
        const bool more = (t0 + TS_) < T_;

        __syncthreads();    // buf[cur] staged (vmcnt drained) + prev compute done

        // issue next tile's staging; flies under this tile's compute
        if (more) {
            stage_glds(nxt, t0 + TS_);
            if (tid < TS_) {
                size_t gi = ((size_t)b * T_ + t0 + TS_ + tid) * H_ + h;
                bbv = bbp[gi]; bdv = bdp[gi];
            }
        }

        const float* EGc = EG[cur];
        const float* KKc = KK[cur];
        const float* QQc = QQ[cur];
        const float* VVc = VV[cur];
        const float* BTc = BT[cur];

        auto ldstep = [&](StepRegs& R, int tt) {
            const float* Ep = EGc + tt * 128;
            const float* Kp = KKc + tt * 128;
            const float* Qp = QQc + tt * 128;
            R.e0 = *(const float4*)(Ep + sl);
            R.e1 = *(const float4*)(Ep + 64 + sl);
            R.k0 = *(const float4*)(Kp + sl);
            R.k1 = *(const float4*)(Kp + 64 + sl);
            R.q0 = *(const float4*)(Qp + sl);
            R.q1 = *(const float4*)(Qp + 64 + sl);
            R.v  = VVc[tt * 16 + colb];
            R.bt = BTc[tt];
        };

        auto compute = [&](const StepRegs& R, int tt) {
            float e[8], kf[8], qf[8];
            *(float4*)&e[0]  = R.e0; *(float4*)&e[4]  = R.e1;
            *(float4*)&kf[0] = R.k0; *(float4*)&kf[4] = R.k1;
            *(float4*)&qf[0] = R.q0; *(float4*)&qf[4] = R.q1;
            const float vcol = R.v;
            const float btv  = R.bt;

            float p0 = 0.0f, p1 = 0.0f;
            #pragma unroll
            for (int j = 0; j < 8; j += 2) {
                S[j]     *= e[j];     p0 += kf[j]     * S[j];
                S[j + 1] *= e[j + 1]; p1 += kf[j + 1] * S[j + 1];
            }
            float p = row16_allreduce(p0 + p1);

            float u = btv * (vcol - p);

            float o0 = 0.0f, o1 = 0.0f;
            #pragma unroll
            for (int j = 0; j < 8; j += 2) {
                S[j]     += kf[j]     * u; o0 += qf[j]     * S[j];
                S[j + 1] += kf[j + 1] * u; o1 += qf[j + 1] * S[j + 1];
            }
            float oo = row16_allreduce(o0 + o1);

            if (kseg == 0) op[ocol + (size_t)(t0 + tt) * HID_] = oo;
        };

        // ---- 16 steps, 2-deep register pipeline (named sets A/B) ----
        StepRegs RA, RB;
        ldstep(RA, 0);
        #pragma unroll
        for (int tp = 0; tp < TS_; tp += 2) {
            ldstep(RB, tp + 1);
            compute(RA, tp);
            if (tp + 2 < TS_) ldstep(RA, tp + 2);
            compute(RB, tp + 1);
        }

        // next tile's beta (loads long since landed; write before barrier)
        if (more && tid < TS_) BT[nxt][tid] = sigmoidf_(bbv + bsign * bdv);
    }
}

// ---------------------------------------------------------------------------
// o = lam*o_f + (1-lam)*o_s -> per-head RMSNorm * onorm_w -> * sigmoid(gate)
// ---------------------------------------------------------------------------
__global__ __launch_bounds__(256) void mix_norm_gate_kernel(
    const float* of, const float* os, const float* lam_pre,
    const float* gate, const float* onorm_w, bf16* outp)
{
    const int bt  = blockIdx.x;
    const int tid = threadIdx.x;
    const size_t row = (size_t)bt * HID_;

    float val[8];
    #pragma unroll
    for (int jj = 0; jj < 8; ++jj) {
        int c = tid + 256 * jj;
        int h = c >> 7;
        float l = sigmoidf_(lam_pre[(size_t)bt * H_ + h]);
        val[jj] = l * of[row + c] + (1.0f - l) * os[row + c];
    }

    __shared__ float red[4][8];
    const int wv = tid >> 6;
    #pragma unroll
    for (int jj = 0; jj < 8; ++jj) {
        float v2 = val[jj] * val[jj];
        #pragma unroll
        for (int m = 1; m < 64; m <<= 1) v2 += __shfl_xor(v2, m);
        if ((tid & 63) == 0) red[wv][jj] = v2;
    }
    __syncthreads();
    const int wb = (tid >> 7) * 2;
    #pragma unroll
    for (int jj = 0; jj < 8; ++jj) {
        int c = tid + 256 * jj;
        float ss   = red[wb][jj] + red[wb + 1][jj];
        float mean = ss * (1.0f / 128.0f);
        float sc   = rsqrtf(mean + 1e-5f) * onorm_w[c & 127];
        float g    = sigmoidf_(gate[row + c]);
        outp[row + c] = (bf16)(val[jj] * sc * g);
    }
}

// ---------------------------------------------------------------------------
extern "C" void kernel_launch(void* const* d_in, const int* in_sizes, int n_in,
                              void* d_out, int out_size, void* d_ws, size_t ws_size,
                              hipStream_t stream) {
    const float* x       = (const float*)d_in[0];
    const float* Wq      = (const float*)d_in[1];
    const float* Wk      = (const float*)d_in[2];
    const float* Wv      = (const float*)d_in[3];
    const float* conv_wq = (const float*)d_in[4];
    const float* conv_wk = (const float*)d_in[5];
    const float* conv_wv = (const float*)d_in[6];
    const float* Wgb1    = (const float*)d_in[7];
    const float* Wgb2    = (const float*)d_in[8];
    const float* Wgd1    = (const float*)d_in[9];
    const float* Wgd2    = (const float*)d_in[10];
    const float* Wbb     = (const float*)d_in[11];
    const float* Wbd     = (const float*)d_in[12];
    const float* Wlam    = (const float*)d_in[13];
    const float* A_log   = (const float*)d_in[14];
    const float* dt_bias = (const float*)d_in[15];
    const float* Wg1     = (const float*)d_in[16];
    const float* Wg2     = (const float*)d_in[17];
    const float* bg2     = (const float*)d_in[18];
    const float* onorm_w = (const float*)d_in[19];
    const float* Wo      = (const float*)d_in[20];
    float* out = (float*)d_out;

    const size_t M = (size_t)B_ * T_;   // 2048

    float* ws = (float*)d_ws;
    size_t off = 0;
    auto alloc = [&](size_t nfloats) { float* p = ws + off; off += nfloats; return p; };

    float* bufQKV = alloc(M * 6528);              // mega preacts; later gfgs+gate
    float* wqkvTf = alloc((size_t)6528 * HID_ / 2);  // [6528,2048] bf16; reused
    float* xbf    = alloc(M * HID_ / 2);          // x bf16; later obf
    float* bufQ   = alloc(M * HID_);              // q fp32
    float* bufK   = alloc(M * HID_);              // k fp32
    float* bufV   = alloc(M * HID_);              // v fp32
    float* bufC   = alloc(M * HID_);              // o_f
    float* bufD   = alloc(M * HID_);              // o_s
    float* midbf  = alloc(M * 384 / 2);           // midb bf16
    float* bb     = alloc(M * H_);
    float* bd     = alloc(M * H_);
    float* lamp   = alloc(M * H_);

    bf16* xb    = (bf16*)xbf;
    bf16* obf   = (bf16*)xbf;                     // reuse after mega-gemm
    bf16* wqkvT = (bf16*)wqkvTf;
    bf16* woT   = wqkvT;                          // [2048,2048] after mega-gemm
    bf16* wcat  = wqkvT + (size_t)HID_ * HID_;    // [4096,256]
    bf16* wgate = wcat + (size_t)4096 * 256;      // [2048,128]
    bf16* midb  = (bf16*)midbf;
    float* gfgs = bufQKV;                         // [2048,4096] after conv
    float* bufE = bufQKV + M * 4096;              // gate [2048,2048]

    dim3 blk(256);
    auto gemm = [&](const bf16* A, const bf16* Bt, const float* bias, void* C,
                    int Mm, int Nn, int Kk, int lda, int ldc, int bf16out) {
        dim3 grid(Nn / 128, Mm / 128);
        mfma_gemm_kernel<<<grid, blk, 0, stream>>>(A, Bt, bias, C, Mm, Nn, Kk,
                                                   lda, ldc, bf16out);
    };
    auto tcast = [&](const float* W, bf16* Wt, int Kk, int Nn) {
        tcast_kernel<<<dim3(Nn / 32, Kk / 32), blk, 0, stream>>>(W, Wt, Kk, Nn);
    };

    // 0) cast x to bf16
    cast_bf16_kernel<<<dim3((unsigned)(M * HID_ / 8 / 256)), blk, 0, stream>>>(x, xb);

    // 1) mega projection: [Wq|Wk|Wv|Wgb1|Wgd1|Wg1], N=6528
    tcast(Wq,   wqkvT,                          HID_, HID_);
    tcast(Wk,   wqkvT + (size_t)2048 * HID_,    HID_, HID_);
    tcast(Wv,   wqkvT + (size_t)4096 * HID_,    HID_, HID_);
    tcast(Wgb1, wqkvT + (size_t)6144 * HID_,    HID_, 128);
    tcast(Wgd1, wqkvT + (size_t)6272 * HID_,    HID_, 128);
    tcast(Wg1,  wqkvT + (size_t)6400 * HID_,    HID_, 128);
    gemm(xb, wqkvT, nullptr, bufQKV, (int)M, 6528, HID_, HID_, 6528, 0);

    // 2) conv + silu (+ l2norm), fp32 outputs
    conv_silu_kernel<<<dim3(B_ * T_), blk, 0, stream>>>(bufQKV, 6528, 0,
        conv_wq, bufQ, 2);
    conv_silu_kernel<<<dim3(B_ * T_), blk, 0, stream>>>(bufQKV, 6528, 2048,
        conv_wk, bufK, 1);
    conv_silu_kernel<<<dim3(B_ * T_), blk, 0, stream>>>(bufQKV, 6528, 4096,
        conv_wv, bufV, 0);

    // 3) mid slice -> bf16
    midcast_kernel<<<dim3((unsigned)(M * 96 / 256)), blk, 0, stream>>>(bufQKV, midb);

    // 4) skinny heads bb/bd/lam
    skinny3_kernel<<<dim3((unsigned)(M / 16)), blk, 0, stream>>>(
        x, Wbb, Wbd, Wlam, bb, bd, lamp);

    // 5) build concat weights and run fused gf/gs expand (N=4096, K=256)
    tcast_off_kernel<<<dim3(64, 4), blk, 0, stream>>>(Wgb2, wcat, HID_, 0,    0,   1.0f);
    tcast_off_kernel<<<dim3(64, 4), blk, 0, stream>>>(Wgd2, wcat, HID_, 0,    128, 1.0f);
    tcast_off_kernel<<<dim3(64, 4), blk, 0, stream>>>(Wgb2, wcat, HID_, 2048, 0,   1.0f);
    tcast_off_kernel<<<dim3(64, 4), blk, 0, stream>>>(Wgd2, wcat, HID_, 2048, 128, -1.0f);
    tcast(Wg2, wgate, 128, HID_);
    tcast(Wo,  woT,   HID_, HID_);
    gemm(midb,       wcat,  nullptr, gfgs, (int)M, 4096, 256, 384, 4096, 0);
    gemm(midb + 256, wgate, bg2,     bufE, (int)M, HID_, 128, 384, HID_, 0);

    // 6) decay gates in place on gfgs
    decay_gate_kernel<<<dim3((unsigned)(M * HID_ / 256)), blk, 0, stream>>>(
        gfgs, A_log, dt_bias);

    // 7) dual-state delta-rule recurrence (512 blocks)
    fkda_kernel<<<dim3(512), blk, 0, stream>>>(bufQ, bufK, bufV,
        gfgs, gfgs + 2048, 4096, bb, bd, bufC, bufD);

    // 8) mix + rmsnorm + gate -> bf16
    mix_norm_gate_kernel<<<dim3(B_ * T_), blk, 0, stream>>>(
        bufC, bufD, lamp, bufE, onorm_w, obf);

    // 9) output projection
    gemm(obf, woT, nullptr, out, (int)M, HID_, HID_, HID_, HID_, 0);
}

// Round 2
// 681.719 us; speedup vs baseline: 1.0957x; 1.0886x over previous
//
#include <hip/hip_runtime.h>
#include <hip/hip_bf16.h>
#include <math.h>
#include <stdint.h>

#define B_   2
#define T_   1024
#define HID_ 2048
#define H_   16
#define DK_  128
#define DV_  128
#define TS_  16     // timesteps staged per LDS tile in recurrence

typedef __bf16 bf16;
typedef __attribute__((ext_vector_type(8))) __bf16 bf16x8;
typedef __attribute__((ext_vector_type(4))) float f32x4;
typedef __attribute__((ext_vector_type(2))) float f32x2;

typedef __attribute__((address_space(3))) uint32_t* lds_ptr_t;
typedef const __attribute__((address_space(1))) uint32_t* glb_ptr_t;

__device__ __forceinline__ float sigmoidf_(float x) {
    return 1.0f / (1.0f + __expf(-x));
}

// async global->LDS, 16B per lane. LDS base wave-uniform (HW: lane i ->
// base + 16*i); global address is per-lane.
__device__ __forceinline__ void ldg_to_lds16(const void* g, void* lds) {
    __builtin_amdgcn_global_load_lds((glb_ptr_t)(uintptr_t)g,
                                     (lds_ptr_t)(uintptr_t)lds, 16, 0, 0);
}

// DPP rotate-add: VALU-latency cross-lane. CTRL = 0x120 + n (row_ror:n).
template <int CTRL>
__device__ __forceinline__ float dpp_ror_add(float x) {
    int yi = __builtin_amdgcn_update_dpp(
        0, __builtin_bit_cast(int, x), CTRL, 0xF, 0xF, true);
    return x + __builtin_bit_cast(float, yi);
}
// all-reduce (sum) across the 16 lanes of a DPP row
__device__ __forceinline__ float row16_allreduce(float x) {
    x = dpp_ror_add<0x128>(x);   // ror 8
    x = dpp_ror_add<0x124>(x);   // ror 4
    x = dpp_ror_add<0x122>(x);   // ror 2
    x = dpp_ror_add<0x121>(x);   // ror 1
    return x;
}

// ---------------------------------------------------------------------------
// fp32 -> bf16 elementwise cast, 8 elems/thread
// ---------------------------------------------------------------------------
__global__ __launch_bounds__(256) void cast_bf16_kernel(
    const float* __restrict__ in, bf16* __restrict__ out)
{
    int i = blockIdx.x * 256 + threadIdx.x;
    float4 a = ((const float4*)in)[2 * i];
    float4 b = ((const float4*)in)[2 * i + 1];
    bf16x8 o;
    o[0] = (bf16)a.x; o[1] = (bf16)a.y; o[2] = (bf16)a.z; o[3] = (bf16)a.w;
    o[4] = (bf16)b.x; o[5] = (bf16)b.y; o[6] = (bf16)b.z; o[7] = (bf16)b.w;
    ((bf16x8*)out)[i] = o;
}

// ---------------------------------------------------------------------------
// W [K,N] fp32  ->  Wt [N,K] bf16 (transpose-cast). 32x32 tiles.
// ---------------------------------------------------------------------------
__global__ __launch_bounds__(256) void tcast_kernel(
    const float* __restrict__ W, bf16* __restrict__ Wt, int K, int N)
{
    __shared__ float tile[32][33];
    const int k0 = blockIdx.y * 32, n0 = blockIdx.x * 32;
    const int r = threadIdx.x >> 5, c = threadIdx.x & 31;
    #pragma unroll
    for (int i = 0; i < 4; ++i)
        tile[r + 8 * i][c] = W[(size_t)(k0 + r + 8 * i) * N + n0 + c];
    __syncthreads();
    #pragma unroll
    for (int i = 0; i < 4; ++i)
        Wt[(size_t)(n0 + r + 8 * i) * K + k0 + c] = (bf16)tile[c][r + 8 * i];
}

// ---------------------------------------------------------------------------
// Transpose-cast with row/col offset + sign into Wt with row-stride 256.
// W [128, N] fp32 -> Wt[(noff+n)*256 + koff + k] = sign * W[k][n].
// Used to build [Wgb2; +/-Wgd2] concatenated K=256 weights.
// ---------------------------------------------------------------------------
__global__ __launch_bounds__(256) void tcast_off_kernel(
    const float* __restrict__ W, bf16* __restrict__ Wt,
    int N, int noff, int koff, float sign)
{
    __shared__ float tile[32][33];
    const int k0 = blockIdx.y * 32, n0 = blockIdx.x * 32;
    const int r = threadIdx.x >> 5, c = threadIdx.x & 31;
    #pragma unroll
    for (int i = 0; i < 4; ++i)
        tile[r + 8 * i][c] = W[(size_t)(k0 + r + 8 * i) * N + n0 + c];
    __syncthreads();
    #pragma unroll
    for (int i = 0; i < 4; ++i)
        Wt[(size_t)(noff + n0 + r + 8 * i) * 256 + koff + k0 + c] =
            (bf16)(sign * tile[c][r + 8 * i]);
}

// ---------------------------------------------------------------------------
// bf16 MFMA GEMM: C[M,N] = A[M,K] @ Bt[N,K]^T (+bias). 128x128 tile, BK=32.
// lda/ldc = element row strides of A/C; Bt row stride = Kfull.
// ---------------------------------------------------------------------------
__global__ __launch_bounds__(256) void mfma_gemm_kernel(
    const bf16* __restrict__ A, const bf16* __restrict__ Bt,
    const float* __restrict__ bias, void* __restrict__ Cout,
    int M, int N, int Kfull, int lda, int ldc, int bf16out)
{
    __shared__ bf16 As[128 * 32];
    __shared__ bf16 Bs[128 * 32];

    const int tid  = threadIdx.x;
    const int w    = tid >> 6;
    const int lane = tid & 63;
    const int n0   = blockIdx.x * 128;
    const int m0   = blockIdx.y * 128;
    const int wm   = (w >> 1) * 64;
    const int wn   = (w & 1) * 64;

    const int lr = lane >> 2;
    const int lc = (lane & 3) * 8;

    f32x4 acc[4][4];
    #pragma unroll
    for (int i = 0; i < 4; ++i)
        #pragma unroll
        for (int j = 0; j < 4; ++j) acc[i][j] = (f32x4)0.0f;

    const bf16* ApL = As + (wm + (lane & 15)) * 32 + (lane >> 4) * 8;
    const bf16* BpL = Bs + (wn + (lane & 15)) * 32 + (lane >> 4) * 8;

    for (int k0 = 0; k0 < Kfull; k0 += 32) {
        #pragma unroll
        for (int i = 0; i < 2; ++i) {
            const int rr = (w * 2 + i) * 16 + lr;
            ldg_to_lds16(A  + (size_t)(m0 + rr) * lda   + k0 + lc, As + (w * 2 + i) * 512);
            ldg_to_lds16(Bt + (size_t)(n0 + rr) * Kfull + k0 + lc, Bs + (w * 2 + i) * 512);
        }
        __syncthreads();

        bf16x8 af[4], bfr[4];
        #pragma unroll
        for (int i = 0; i < 4; ++i) af[i]  = *(const bf16x8*)(ApL + i * 16 * 32);
        #pragma unroll
        for (int j = 0; j < 4; ++j) bfr[j] = *(const bf16x8*)(BpL + j * 16 * 32);
        #pragma unroll
        for (int i = 0; i < 4; ++i)
            #pragma unroll
            for (int j = 0; j < 4; ++j)
                acc[i][j] = __builtin_amdgcn_mfma_f32_16x16x32_bf16(
                    af[i], bfr[j], acc[i][j], 0, 0, 0);
        __syncthreads();
    }

    #pragma unroll
    for (int i = 0; i < 4; ++i) {
        const int row = m0 + wm + i * 16 + (lane >> 4) * 4;
        #pragma unroll
        for (int j = 0; j < 4; ++j) {
            const int col = n0 + wn + j * 16 + (lane & 15);
            const float bv = bias ? bias[col] : 0.0f;
            #pragma unroll
            for (int r = 0; r < 4; ++r) {
                float v = acc[i][j][r] + bv;
                if (bf16out) ((bf16*)Cout)[(size_t)(row + r) * ldc + col] = (bf16)v;
                else ((float*)Cout)[(size_t)(row + r) * ldc + col] = v;
            }
        }
    }
}

// ---------------------------------------------------------------------------
// Cast mid slice of mega-GEMM output (cols 6144..6527 of [M,6528]) -> bf16
// midb [M,384]. 4 cols/thread.
// ---------------------------------------------------------------------------
__global__ __launch_bounds__(256) void midcast_kernel(
    const float* __restrict__ src, bf16* __restrict__ midb)
{
    int i = blockIdx.x * 256 + threadIdx.x;   // over 2048*96
    int m = i / 96, c4 = i - m * 96;
    float4 v = *(const float4*)(src + (size_t)m * 6528 + 6144 + c4 * 4);
    bf16 o[4] = {(bf16)v.x, (bf16)v.y, (bf16)v.z, (bf16)v.w};
    *(uint64_t*)(midb + (size_t)m * 384 + c4 * 4) = *(uint64_t*)o;
}

// ---------------------------------------------------------------------------
// Fused skinny GEMMs: bb/bd/lam = x @ {Wbb,Wbd,Wlam}  (N=16 each, K=2048).
// ---------------------------------------------------------------------------
__global__ __launch_bounds__(256) void skinny3_kernel(
    const float* __restrict__ x, const float* __restrict__ Wbb,
    const float* __restrict__ Wbd, const float* __restrict__ Wlam,
    float* __restrict__ bb, float* __restrict__ bd, float* __restrict__ lam)
{
    __shared__ float xs[16][128];
    __shared__ float wsh[128][48];
    const int m0  = blockIdx.x * 16;
    const int tid = threadIdx.x;
    const int r = tid >> 4, cg = tid & 15;
    float acc0 = 0.f, acc1 = 0.f, acc2 = 0.f;

    for (int k0 = 0; k0 < HID_; k0 += 128) {
        __syncthreads();
        #pragma unroll
        for (int i = 0; i < 2; ++i) {
            int f = tid + 256 * i;
            int rr = f >> 5, cc = (f & 31) * 4;
            *(float4*)&xs[rr][cc] = *(const float4*)(x + (size_t)(m0 + rr) * HID_ + k0 + cc);
        }
        #pragma unroll
        for (int i = 0; i < 2; ++i) {
            int f = tid + 256 * i;
            int kk = f >> 2, cc = (f & 3) * 4;
            *(float4*)&wsh[kk][cc]      = *(const float4*)(Wbb  + (size_t)(k0 + kk) * 16 + cc);
            *(float4*)&wsh[kk][16 + cc] = *(const float4*)(Wbd  + (size_t)(k0 + kk) * 16 + cc);
            *(float4*)&wsh[kk][32 + cc] = *(const float4*)(Wlam + (size_t)(k0 + kk) * 16 + cc);
        }
        __syncthreads();
        #pragma unroll 8
        for (int kk = 0; kk < 128; ++kk) {
            float xv = xs[r][kk];
            acc0 += xv * wsh[kk][cg];
            acc1 += xv * wsh[kk][16 + cg];
            acc2 += xv * wsh[kk][32 + cg];
        }
    }
    size_t o = (size_t)(m0 + r) * 16 + cg;
    bb[o] = acc0; bd[o] = acc1; lam[o] = acc2;
}

// ---------------------------------------------------------------------------
// Causal depthwise conv1d (K=4) + SiLU, + optional per-head l2norm.
// Reads strided slice of mega-GEMM pre-activations. fp32 out.
// mode: 0 = silu only (v); 1 = + l2norm (k); 2 = + l2norm * DK^-0.5 (q)
// ---------------------------------------------------------------------------
__global__ __launch_bounds__(256) void conv_silu_kernel(
    const float* __restrict__ xin, int ldx, int coloff,
    const float* __restrict__ w, float* __restrict__ yout, int mode)
{
    const int bt  = blockIdx.x;
    const int t   = bt & (T_ - 1);
    const int tid = threadIdx.x;
    const float* xr = xin + (size_t)bt * ldx + coloff;

    float val[8];
    #pragma unroll
    for (int jj = 0; jj < 8; ++jj) {
        int c = tid + 256 * jj;
        float4 wc = *(const float4*)(w + (size_t)c * 4);
        const float* xc = xr + c;
        float acc = wc.w * xc[0];
        if (t >= 1) acc += wc.z * xc[-ldx];
        if (t >= 2) acc += wc.y * xc[-2 * ldx];
        if (t >= 3) acc += wc.x * xc[-3 * ldx];
        val[jj] = acc * sigmoidf_(acc);
    }

    if (mode > 0) {
        __shared__ float red[4][8];
        const int wv = tid >> 6;
        #pragma unroll
        for (int jj = 0; jj < 8; ++jj) {
            float v2 = val[jj] * val[jj];
            #pragma unroll
            for (int m = 1; m < 64; m <<= 1) v2 += __shfl_xor(v2, m);
            if ((tid & 63) == 0) red[wv][jj] = v2;
        }
        __syncthreads();
        const int wb = (tid >> 7) * 2;
        #pragma unroll
        for (int jj = 0; jj < 8; ++jj) {
            float ss = red[wb][jj] + red[wb + 1][jj];
            float sc = rsqrtf(ss + 1e-6f);
            if (mode == 2) sc *= 0.08838834764831845f;     // DK^-0.5
            val[jj] *= sc;
        }
    }

    const size_t row = (size_t)bt * HID_;
    #pragma unroll
    for (int jj = 0; jj < 8; ++jj)
        yout[row + tid + 256 * jj] = val[jj];
}

// ---------------------------------------------------------------------------
// Decay gates, in place on gfgs [M,4096] (cols 0..2047 = gf, 2048.. = gs):
// x <- exp(-exp(A_log[h]) * softplus(x + dtb))
// ---------------------------------------------------------------------------
__global__ __launch_bounds__(256) void decay_gate_kernel(
    float* gfgs, const float* __restrict__ A_log,
    const float* __restrict__ dt_bias)
{
    size_t i = (size_t)blockIdx.x * 256 + threadIdx.x;   // over M*2048
    int c = (int)(i & (HID_ - 1));
    size_t m = i >> 11;
    int h = c >> 7;
    float* pf = gfgs + m * 4096 + c;
    float* ps = pf + 2048;
    float na = -__expf(A_log[h]);
    float db = dt_bias[c];
    float xf = *pf + db;
    float xs = *ps + db;
    float spf = (xf > 20.0f) ? xf : log1pf(__expf(xf));
    float sps = (xs > 20.0f) ? xs : log1pf(__expf(xs));
    *pf = __expf(na * spf);
    *ps = __expf(na * sps);
}

// ---------------------------------------------------------------------------
// Dual-state gated delta-rule recurrence, v6: packed-math + issue-lean.
//  - all channel math as f32x2 (v_pk_mul_f32 / v_pk_fma_f32): 32 scalar
//    ops -> ~19 packed ops per step per lane.
//  - ONE global store per tile per lane (was 16 predicated stores): per
//    step a cndmask keeps oo on the lane where kseg==tt; at tile end all
//    64 lanes store distinct (t,col) elements. Store is issued AFTER the
//    next tile's barrier+staging so its ack hides under 16 steps.
//  - double-buffered LDS, staging for tile t+1 issued right after the
//    barrier (flies under tile t's compute); 2-deep named-reg pipeline.
// Grid: 512 blocks: bx = sv*32 + bh;  bh = b*16+h, sv = s*8+vc.
// Block: 256 threads = 4 waves; wave = 4 cols x 16 ksegs (8 k-chan each).
// LDS slot layout per row (128 floats): slot l<16 holds channels 8l..8l+3,
// slot l>=16 holds 8(l-16)+4..8(l-16)+7  -> each b128 read is 2-way/bank.
// ---------------------------------------------------------------------------
__global__ __launch_bounds__(256) void fkda_kernel(
    const float* __restrict__ qp, const float* __restrict__ kp,
    const float* __restrict__ vp, const float* __restrict__ egf,
    const float* __restrict__ egs, int ldeg,
    const float* __restrict__ bbp, const float* __restrict__ bdp,
    float* __restrict__ ofp, float* __restrict__ osp)
{
    const int bx = blockIdx.x;
    const int bh = bx & 31;
    const int sv = bx >> 5;
    const int b  = bh >> 4;
    const int h  = bh & 15;
    const int s  = sv >> 3;
    const int vc = sv & 7;

    const float* eg = s ? egs : egf;
    float*       op = s ? osp : ofp;
    const float  bsign = s ? -1.0f : 1.0f;

    const int tid  = threadIdx.x;
    const int lane = tid & 63;
    const int w    = tid >> 6;
    const int kseg = lane & 15;
    const int colb = w * 4 + (lane >> 4);

    const size_t base  = (size_t)b * T_ * HID_ + (size_t)h * DK_;
    const size_t baseg = (size_t)b * T_ * ldeg + (size_t)h * DK_;
    const size_t ocol  = base + (size_t)vc * 16 + colb;

    __shared__ float EG[2][TS_ * 128];     // 8 KB each buf
    __shared__ float KK[2][TS_ * 128];
    __shared__ float QQ[2][TS_ * 128];
    __shared__ float VV[2][TS_ * 16];
    __shared__ float BT[2][TS_];

    f32x2 S0 = {0.f, 0.f}, S1 = {0.f, 0.f}, S2 = {0.f, 0.f}, S3 = {0.f, 0.f};

    // staging lane map: flat word W = n*256 + 4*lane must hold row tt's
    // swizzled slot; lane fetches the matching global channel.
    const int l5  = lane & 31;
    const int ttl = lane >> 5;
    const int cg  = (l5 < 16) ? (l5 * 8) : ((l5 - 16) * 8 + 4);
    const int sl  = kseg * 4;    // read slot word base

    // issue all async global->LDS staging for the tile starting at t0
    auto stage_glds = [&](int bi, int t0) {
        #pragma unroll
        for (int i = 0; i < 2; ++i) {
            int n  = w * 2 + i;
            int tt = n * 2 + ttl;
            size_t rq = base  + (size_t)(t0 + tt) * HID_ + cg;
            size_t rg = baseg + (size_t)(t0 + tt) * ldeg + cg;
            ldg_to_lds16(eg + rg, &EG[bi][n * 256]);
            ldg_to_lds16(kp + rq, &KK[bi][n * 256]);
            ldg_to_lds16(qp + rq, &QQ[bi][n * 256]);
        }
        if (tid < 64) {       // V: 16t x 16cols fp32, lane l -> tt=l>>2
            int tt2 = tid >> 2, vo = (tid & 3) * 4;
            size_t g = base + (size_t)(t0 + tt2) * HID_ + vc * 16 + vo;
            ldg_to_lds16(vp + g, &VV[bi][0]);
        }
    };

    // ---- prologue: stage tile 0 (incl. beta) ----
    float bbv = 0.0f, bdv = 0.0f;
    if (tid < TS_) {
        size_t gi = ((size_t)b * T_ + tid) * H_ + h;
        bbv = bbp[gi]; bdv = bdp[gi];
    }
    stage_glds(0, 0);
    if (tid < TS_) BT[0][tid] = sigmoidf_(bbv + bsign * bdv);

    float ooPrev = 0.0f;       // held output element from previous tile

    for (int t0 = 0; t0 < T_; t0 += TS_) {
        const int cur = (t0 >> 4) & 1;
        const int nxt = cur ^ 1;
        const bool more = (t0 + TS_) < T_;

        __syncthreads();    // buf[cur] staged (vmcnt drained) + prev compute done

        // issue next tile's staging; flies under this tile's compute
        if (more) {
            stage_glds(nxt, t0 + TS_);
            if (tid < TS_) {
                size_t gi = ((size_t)b * T_ + t0 + TS_ + tid) * H_ + h;
                bbv = bbp[gi]; bdv = bdp[gi];
            }
        }

        // store previous tile's output element (ack hides under compute)
        if (t0) op[ocol + (size_t)(t0 - TS_ + kseg) * HID_] = ooPrev;

        const float* Eb = &EG[cur][sl];
        const float* Kb = &KK[cur][sl];
        const float* Qb = &QQ[cur][sl];
        const float* Vc = &VV[cur][colb];
        const float* Bc = &BT[cur][0];

        float oo = 0.0f;

        auto step = [&](const float4& ef0, const float4& ef1,
                        const float4& kf0, const float4& kf1,
                        const float4& qf0, const float4& qf1,
                        float v, float bt, int tt) {
            f32x2 e0 = {ef0.x, ef0.y}, e1 = {ef0.z, ef0.w};
            f32x2 e2 = {ef1.x, ef1.y}, e3 = {ef1.z, ef1.w};
            f32x2 k0 = {kf0.x, kf0.y}, k1 = {kf0.z, kf0.w};
            f32x2 k2 = {kf1.x, kf1.y}, k3 = {kf1.z, kf1.w};
            f32x2 q0 = {qf0.x, qf0.y}, q1 = {qf0.z, qf0.w};
            f32x2 q2 = {qf1.x, qf1.y}, q3 = {qf1.z, qf1.w};

            S0 *= e0; S1 *= e1; S2 *= e2; S3 *= e3;
            f32x2 pa = k0 * S0 + k1 * S1;
            f32x2 pb = k2 * S2 + k3 * S3;
            f32x2 ps = pa + pb;
            float p = row16_allreduce(ps.x + ps.y);

            float u = bt * (v - p);
            f32x2 u2 = {u, u};
            S0 += k0 * u2; S1 += k1 * u2; S2 += k2 * u2; S3 += k3 * u2;
            f32x2 oa = q0 * S0 + q1 * S1;
            f32x2 ob = q2 * S2 + q3 * S3;
            f32x2 om = oa + ob;
            float o = row16_allreduce(om.x + om.y);

            oo = (tt == kseg) ? o : oo;   // keep own timestep's value
        };

        #define LDSTEP(tt, E0, E1, K0, K1, Q0, Q1, V, BTv)          \
            E0 = *(const float4*)(Eb + (tt) * 128);                  \
            E1 = *(const float4*)(Eb + (tt) * 128 + 64);             \
            K0 = *(const float4*)(Kb + (tt) * 128);                  \
            K1 = *(const float4*)(Kb + (tt) * 128 + 64);             \
            Q0 = *(const float4*)(Qb + (tt) * 128);                  \
            Q1 = *(const float4*)(Qb + (tt) * 128 + 64);             \
            V  = Vc[(tt) * 16];                                      \
            BTv = Bc[(tt)];

        // ---- 16 steps, 2-deep register pipeline (named sets A/B) ----
        float4 eA0, eA1, kA0, kA1, qA0, qA1;
        float4 eB0, eB1, kB0, kB1, qB0, qB1;
        float  vA, btA, vB, btB;

        LDSTEP(0, eA0, eA1, kA0, kA1, qA0, qA1, vA, btA);
        #pragma unroll
        for (int tp = 0; tp < TS_; tp += 2) {
            LDSTEP(tp + 1, eB0, eB1, kB0, kB1, qB0, qB1, vB, btB);
            step(eA0, eA1, kA0, kA1, qA0, qA1, vA, btA, tp);
            if (tp + 2 < TS_) {
                LDSTEP(tp + 2, eA0, eA1, kA0, kA1, qA0, qA1, vA, btA);
            }
            step(eB0, eB1, kB0, kB1, qB0, qB1, vB, btB, tp + 1);
        }
        #undef LDSTEP

        ooPrev = oo;

        // next tile's beta (loads long since landed; write before barrier)
        if (more && tid < TS_) BT[nxt][tid] = sigmoidf_(bbv + bsign * bdv);
    }

    // epilogue: store last tile's outputs
    op[ocol + (size_t)(T_ - TS_ + kseg) * HID_] = ooPrev;
}

// ---------------------------------------------------------------------------
// o = lam*o_f + (1-lam)*o_s -> per-head RMSNorm * onorm_w -> * sigmoid(gate)
// ---------------------------------------------------------------------------
__global__ __launch_bounds__(256) void mix_norm_gate_kernel(
    const float* of, const float* os, const float* lam_pre,
    const float* gate, const float* onorm_w, bf16* outp)
{
    const int bt  = blockIdx.x;
    const int tid = threadIdx.x;
    const size_t row = (size_t)bt * HID_;

    float val[8];
    #pragma unroll
    for (int jj = 0; jj < 8; ++jj) {
        int c = tid + 256 * jj;
        int h = c >> 7;
        float l = sigmoidf_(lam_pre[(size_t)bt * H_ + h]);
        val[jj] = l * of[row + c] + (1.0f - l) * os[row + c];
    }

    __shared__ float red[4][8];
    const int wv = tid >> 6;
    #pragma unroll
    for (int jj = 0; jj < 8; ++jj) {
        float v2 = val[jj] * val[jj];
        #pragma unroll
        for (int m = 1; m < 64; m <<= 1) v2 += __shfl_xor(v2, m);
        if ((tid & 63) == 0) red[wv][jj] = v2;
    }
    __syncthreads();
    const int wb = (tid >> 7) * 2;
    #pragma unroll
    for (int jj = 0; jj < 8; ++jj) {
        int c = tid + 256 * jj;
        float ss   = red[wb][jj] + red[wb + 1][jj];
        float mean = ss * (1.0f / 128.0f);
        float sc   = rsqrtf(mean + 1e-5f) * onorm_w[c & 127];
        float g    = sigmoidf_(gate[row + c]);
        outp[row + c] = (bf16)(val[jj] * sc * g);
    }
}

// ---------------------------------------------------------------------------
extern "C" void kernel_launch(void* const* d_in, const int* in_sizes, int n_in,
                              void* d_out, int out_size, void* d_ws, size_t ws_size,
                              hipStream_t stream) {
    const float* x       = (const float*)d_in[0];
    const float* Wq      = (const float*)d_in[1];
    const float* Wk      = (const float*)d_in[2];
    const float* Wv      = (const float*)d_in[3];
    const float* conv_wq = (const float*)d_in[4];
    const float* conv_wk = (const float*)d_in[5];
    const float* conv_wv = (const float*)d_in[6];
    const float* Wgb1    = (const float*)d_in[7];
    const float* Wgb2    = (const float*)d_in[8];
    const float* Wgd1    = (const float*)d_in[9];
    const float* Wgd2    = (const float*)d_in[10];
    const float* Wbb     = (const float*)d_in[11];
    const float* Wbd     = (const float*)d_in[12];
    const float* Wlam    = (const float*)d_in[13];
    const float* A_log   = (const float*)d_in[14];
    const float* dt_bias = (const float*)d_in[15];
    const float* Wg1     = (const float*)d_in[16];
    const float* Wg2     = (const float*)d_in[17];
    const float* bg2     = (const float*)d_in[18];
    const float* onorm_w = (const float*)d_in[19];
    const float* Wo      = (const float*)d_in[20];
    float* out = (float*)d_out;

    const size_t M = (size_t)B_ * T_;   // 2048

    float* ws = (float*)d_ws;
    size_t off = 0;
    auto alloc = [&](size_t nfloats) { float* p = ws + off; off += nfloats; return p; };

    float* bufQKV = alloc(M * 6528);              // mega preacts; later gfgs+gate
    float* wqkvTf = alloc((size_t)6528 * HID_ / 2);  // [6528,2048] bf16; reused
    float* xbf    = alloc(M * HID_ / 2);          // x bf16; later obf
    float* bufQ   = alloc(M * HID_);              // q fp32
    float* bufK   = alloc(M * HID_);              // k fp32
    float* bufV   = alloc(M * HID_);              // v fp32
    float* bufC   = alloc(M * HID_);              // o_f
    float* bufD   = alloc(M * HID_);              // o_s
    float* midbf  = alloc(M * 384 / 2);           // midb bf16
    float* bb     = alloc(M * H_);
    float* bd     = alloc(M * H_);
    float* lamp   = alloc(M * H_);

    bf16* xb    = (bf16*)xbf;
    bf16* obf   = (bf16*)xbf;                     // reuse after mega-gemm
    bf16* wqkvT = (bf16*)wqkvTf;
    bf16* woT   = wqkvT;                          // [2048,2048] after mega-gemm
    bf16* wcat  = wqkvT + (size_t)HID_ * HID_;    // [4096,256]
    bf16* wgate = wcat + (size_t)4096 * 256;      // [2048,128]
    bf16* midb  = (bf16*)midbf;
    float* gfgs = bufQKV;                         // [2048,4096] after conv
    float* bufE = bufQKV + M * 4096;              // gate [2048,2048]

    dim3 blk(256);
    auto gemm = [&](const bf16* A, const bf16* Bt, const float* bias, void* C,
                    int Mm, int Nn, int Kk, int lda, int ldc, int bf16out) {
        dim3 grid(Nn / 128, Mm / 128);
        mfma_gemm_kernel<<<grid, blk, 0, stream>>>(A, Bt, bias, C, Mm, Nn, Kk,
                                                   lda, ldc, bf16out);
    };
    auto tcast = [&](const float* W, bf16* Wt, int Kk, int Nn) {
        tcast_kernel<<<dim3(Nn / 32, Kk / 32), blk, 0, stream>>>(W, Wt, Kk, Nn);
    };

    // 0) cast x to bf16
    cast_bf16_kernel<<<dim3((unsigned)(M * HID_ / 8 / 256)), blk, 0, stream>>>(x, xb);

    // 1) mega projection: [Wq|Wk|Wv|Wgb1|Wgd1|Wg1], N=6528
    tcast(Wq,   wqkvT,                          HID_, HID_);
    tcast(Wk,   wqkvT + (size_t)2048 * HID_,    HID_, HID_);
    tcast(Wv,   wqkvT + (size_t)4096 * HID_,    HID_, HID_);
    tcast(Wgb1, wqkvT + (size_t)6144 * HID_,    HID_, 128);
    tcast(Wgd1, wqkvT + (size_t)6272 * HID_,    HID_, 128);
    tcast(Wg1,  wqkvT + (size_t)6400 * HID_,    HID_, 128);
    gemm(xb, wqkvT, nullptr, bufQKV, (int)M, 6528, HID_, HID_, 6528, 0);

    // 2) conv + silu (+ l2norm), fp32 outputs
    conv_silu_kernel<<<dim3(B_ * T_), blk, 0, stream>>>(bufQKV, 6528, 0,
        conv_wq, bufQ, 2);
    conv_silu_kernel<<<dim3(B_ * T_), blk, 0, stream>>>(bufQKV, 6528, 2048,
        conv_wk, bufK, 1);
    conv_silu_kernel<<<dim3(B_ * T_), blk, 0, stream>>>(bufQKV, 6528, 4096,
        conv_wv, bufV, 0);

    // 3) mid slice -> bf16
    midcast_kernel<<<dim3((unsigned)(M * 96 / 256)), blk, 0, stream>>>(bufQKV, midb);

    // 4) skinny heads bb/bd/lam
    skinny3_kernel<<<dim3((unsigned)(M / 16)), blk, 0, stream>>>(
        x, Wbb, Wbd, Wlam, bb, bd, lamp);

    // 5) build concat weights and run fused gf/gs expand (N=4096, K=256)
    tcast_off_kernel<<<dim3(64, 4), blk, 0, stream>>>(Wgb2, wcat, HID_, 0,    0,   1.0f);
    tcast_off_kernel<<<dim3(64, 4), blk, 0, stream>>>(Wgd2, wcat, HID_, 0,    128, 1.0f);
    tcast_off_kernel<<<dim3(64, 4), blk, 0, stream>>>(Wgb2, wcat, HID_, 2048, 0,   1.0f);
    tcast_off_kernel<<<dim3(64, 4), blk, 0, stream>>>(Wgd2, wcat, HID_, 2048, 128, -1.0f);
    tcast(Wg2, wgate, 128, HID_);
    tcast(Wo,  woT,   HID_, HID_);
    gemm(midb,       wcat,  nullptr, gfgs, (int)M, 4096, 256, 384, 4096, 0);
    gemm(midb + 256, wgate, bg2,     bufE, (int)M, HID_, 128, 384, HID_, 0);

    // 6) decay gates in place on gfgs
    decay_gate_kernel<<<dim3((unsigned)(M * HID_ / 256)), blk, 0, stream>>>(
        gfgs, A_log, dt_bias);

    // 7) dual-state delta-rule recurrence (512 blocks)
    fkda_kernel<<<dim3(512), blk, 0, stream>>>(bufQ, bufK, bufV,
        gfgs, gfgs + 2048, 4096, bb, bd, bufC, bufD);

    // 8) mix + rmsnorm + gate -> bf16
    mix_norm_gate_kernel<<<dim3(B_ * T_), blk, 0, stream>>>(
        bufC, bufD, lamp, bufE, onorm_w, obf);

    // 9) output projection
    gemm(obf, woT, nullptr, out, (int)M, HID_, HID_, HID_, HID_, 0);
}